// Round 1
// baseline (1026.649 us; speedup 1.0000x reference)
//
#include <hip/hip_runtime.h>

typedef __attribute__((ext_vector_type(8))) short short8;   // 8 bf16 = 4 VGPRs (MFMA A/B frag)
typedef __attribute__((ext_vector_type(4))) float f32x4;    // MFMA C/D frag
typedef __attribute__((ext_vector_type(4))) short short4v;

#define DM 768
#define DP 64

__device__ __forceinline__ unsigned short f2bf(float f) {
  unsigned u = __float_as_uint(f);
  u = u + 0x7fffu + ((u >> 16) & 1u);          // RNE
  return (unsigned short)(u >> 16);
}
__device__ __forceinline__ float bf2f(unsigned short s) {
  return __uint_as_float(((unsigned)s) << 16);
}
// mish(v) = v*tanh(softplus(v)) = v*(t^2+2t)/(t^2+2t+2), t=e^v (exact algebra, one exp)
__device__ __forceinline__ float mishf(float v) {
  float t = __expf(fminf(v, 30.0f));
  float num = t * (t + 2.0f);
  return v * (num / (num + 2.0f));
}

// dst[n*K + k] = bf16(src[k*N + n])  (transpose + fp32->bf16)
__global__ void cvt_transpose(const float* __restrict__ src,
                              unsigned short* __restrict__ dst, int K, int N) {
  int i = blockIdx.x * 256 + threadIdx.x;
  if (i >= K * N) return;
  int n = i / K;
  int k = i - n * K;
  dst[i] = f2bf(src[k * N + n]);
}

__global__ __launch_bounds__(512, 2) void fused_policy(
    const float* __restrict__ x, const float* __restrict__ b1,
    const float* __restrict__ bq, const float* __restrict__ bk,
    const float* __restrict__ Wp, const float* __restrict__ bp,
    const int* __restrict__ idxs, int n_idx,
    const unsigned short* __restrict__ W1t,   // [768 n][768 k] bf16
    const unsigned short* __restrict__ Wqt,   // [64 n][768 k] bf16
    const unsigned short* __restrict__ Wkt,   // [64 n][768 k] bf16
    float* __restrict__ out) {
  constexpr int XS_STRIDE = 136;   // 64x128 bf16 chunk, +8 pad
  constexpr int HS_STRIDE = 776;   // 768 + 8 pad (stride%32dw==4 -> even bank spread)
  constexpr int QK_STRIDE = 72;

  __shared__ __align__(16) unsigned char smem0[64 * XS_STRIDE * 2];  // xs, later sc
  __shared__ __align__(16) unsigned short hs[64 * HS_STRIDE];
  __shared__ __align__(16) unsigned short qsh[64 * QK_STRIDE];
  __shared__ __align__(16) unsigned short qsl[64 * QK_STRIDE];
  __shared__ __align__(16) unsigned short ksh[64 * QK_STRIDE];
  __shared__ __align__(16) unsigned short ksl[64 * QK_STRIDE];
  __shared__ float promf[32];

  unsigned short* xs = (unsigned short*)smem0;
  float* sc = (float*)smem0;                   // alias: xs dead after P1, sc written P3

  const int b    = blockIdx.x;
  const int tid  = threadIdx.x;
  const int wave = tid >> 6;
  const int lane = tid & 63;
  const int m16  = lane & 15;
  const int quad = lane >> 4;

  const float* xb = x + (size_t)b * (64 * DM);

  // ---------------- P1: h = mish(x @ W1 + b1), h kept in 64x768 register tile ----
  f32x4 acc[4][6];
  #pragma unroll
  for (int rt = 0; rt < 4; ++rt)
    #pragma unroll
    for (int ct = 0; ct < 6; ++ct)
      #pragma unroll
      for (int r = 0; r < 4; ++r) acc[rt][ct][r] = 0.0f;

  const int bcol0 = wave * 96 + m16;
  float b1v[6];
  #pragma unroll
  for (int ct = 0; ct < 6; ++ct) b1v[ct] = b1[bcol0 + ct * 16];

  short8 bcur[6], bnxt[6];
  #pragma unroll
  for (int ct = 0; ct < 6; ++ct)
    bcur[ct] = *(const short8*)(W1t + (bcol0 + ct * 16) * DM + quad * 8);

  for (int c = 0; c < 6; ++c) {
    const int kbase = c * 128;
    __syncthreads();
    // stage 64x128 fp32 -> bf16 chunk into LDS (coalesced float4)
    #pragma unroll
    for (int u = 0; u < 4; ++u) {
      int e = u * 512 + tid;           // float4 index in chunk
      int row = e >> 5;
      int colc = e & 31;
      float4 v = *(const float4*)(xb + row * DM + kbase + colc * 4);
      short4v s4;
      s4.x = (short)f2bf(v.x); s4.y = (short)f2bf(v.y);
      s4.z = (short)f2bf(v.z); s4.w = (short)f2bf(v.w);
      *(short4v*)(xs + row * XS_STRIDE + colc * 4) = s4;
    }
    __syncthreads();
    #pragma unroll
    for (int ks = 0; ks < 4; ++ks) {
      const int kt = c * 4 + ks;
      short8 af[4];
      #pragma unroll
      for (int rt = 0; rt < 4; ++rt)
        af[rt] = *(const short8*)(xs + (rt * 16 + m16) * XS_STRIDE + ks * 32 + quad * 8);
      if (kt < 23) {   // prefetch next K-step's B frags (L2-resident W1t)
        #pragma unroll
        for (int ct = 0; ct < 6; ++ct)
          bnxt[ct] = *(const short8*)(W1t + (bcol0 + ct * 16) * DM + (kt + 1) * 32 + quad * 8);
      }
      #pragma unroll
      for (int rt = 0; rt < 4; ++rt)
        #pragma unroll
        for (int ct = 0; ct < 6; ++ct)
          acc[rt][ct] = __builtin_amdgcn_mfma_f32_16x16x32_bf16(af[rt], bcur[ct], acc[rt][ct], 0, 0, 0);
      if (kt < 23) {
        #pragma unroll
        for (int ct = 0; ct < 6; ++ct) bcur[ct] = bnxt[ct];
      }
    }
  }

  // epilogue: bias + mish -> hs (bf16). C/D layout: row=quad*4+r, col=m16
  #pragma unroll
  for (int rt = 0; rt < 4; ++rt)
    #pragma unroll
    for (int ct = 0; ct < 6; ++ct)
      #pragma unroll
      for (int r = 0; r < 4; ++r) {
        int row = rt * 16 + quad * 4 + r;
        int col = bcol0 + ct * 16;
        hs[row * HS_STRIDE + col] = f2bf(mishf(acc[rt][ct][r] + b1v[ct]));
      }
  __syncthreads();

  // ---------------- P2: q = h@Wq+bq (waves 0-3), k = h@Wk+bk (waves 4-7) --------
  {
    const unsigned short* Wt = (wave < 4) ? Wqt : Wkt;
    const float* bias = (wave < 4) ? bq : bk;
    unsigned short* oh = (wave < 4) ? qsh : ksh;
    unsigned short* ol = (wave < 4) ? qsl : ksl;
    const int rt = wave & 3;

    f32x4 acc2[4];
    #pragma unroll
    for (int ct = 0; ct < 4; ++ct)
      #pragma unroll
      for (int r = 0; r < 4; ++r) acc2[ct][r] = 0.0f;

    short8 c2[4], n2[4];
    #pragma unroll
    for (int ct = 0; ct < 4; ++ct)
      c2[ct] = *(const short8*)(Wt + (ct * 16 + m16) * DM + quad * 8);

    const int arow = (rt * 16 + m16) * HS_STRIDE;
    for (int kt = 0; kt < 24; ++kt) {
      const int k0 = kt * 32;
      short8 a = *(const short8*)(hs + arow + k0 + quad * 8);
      if (kt < 23) {
        #pragma unroll
        for (int ct = 0; ct < 4; ++ct)
          n2[ct] = *(const short8*)(Wt + (ct * 16 + m16) * DM + (k0 + 32) + quad * 8);
      }
      #pragma unroll
      for (int ct = 0; ct < 4; ++ct)
        acc2[ct] = __builtin_amdgcn_mfma_f32_16x16x32_bf16(a, c2[ct], acc2[ct], 0, 0, 0);
      if (kt < 23) {
        #pragma unroll
        for (int ct = 0; ct < 4; ++ct) c2[ct] = n2[ct];
      }
    }
    // split fp32 -> hi/lo bf16 so scores can be error-compensated
    #pragma unroll
    for (int ct = 0; ct < 4; ++ct)
      #pragma unroll
      for (int r = 0; r < 4; ++r) {
        int row = rt * 16 + quad * 4 + r;
        int col = ct * 16 + m16;
        float v = acc2[ct][r] + bias[col];
        unsigned short vh = f2bf(v);
        unsigned short vl = f2bf(v - bf2f(vh));
        oh[row * QK_STRIDE + col] = vh;
        ol[row * QK_STRIDE + col] = vl;
      }
  }
  __syncthreads();

  // ---------------- P3: scores = q@k^T * 0.125 (waves 0-3) | promotion (wave 4) --
  if (wave < 4) {
    const int rt = wave;
    f32x4 acc3[4];
    #pragma unroll
    for (int ct = 0; ct < 4; ++ct)
      #pragma unroll
      for (int r = 0; r < 4; ++r) acc3[ct][r] = 0.0f;

    #pragma unroll
    for (int kt = 0; kt < 2; ++kt) {
      const int k0 = kt * 32;
      short8 ah = *(const short8*)(qsh + (rt * 16 + m16) * QK_STRIDE + k0 + quad * 8);
      short8 al = *(const short8*)(qsl + (rt * 16 + m16) * QK_STRIDE + k0 + quad * 8);
      #pragma unroll
      for (int ct = 0; ct < 4; ++ct) {
        short8 bh = *(const short8*)(ksh + (ct * 16 + m16) * QK_STRIDE + k0 + quad * 8);
        short8 bl = *(const short8*)(ksl + (ct * 16 + m16) * QK_STRIDE + k0 + quad * 8);
        acc3[ct] = __builtin_amdgcn_mfma_f32_16x16x32_bf16(ah, bh, acc3[ct], 0, 0, 0);
        acc3[ct] = __builtin_amdgcn_mfma_f32_16x16x32_bf16(ah, bl, acc3[ct], 0, 0, 0);
        acc3[ct] = __builtin_amdgcn_mfma_f32_16x16x32_bf16(al, bh, acc3[ct], 0, 0, 0);
      }
    }
    #pragma unroll
    for (int ct = 0; ct < 4; ++ct)
      #pragma unroll
      for (int r = 0; r < 4; ++r)
        sc[(rt * 16 + quad * 4 + r) * 64 + ct * 16 + m16] = acc3[ct][r] * 0.125f;
  } else if (wave == 4 && lane < 32) {
    // promf[rr][c] = bp[c] + sum_d k[56+rr][d] * Wp[d][c]
    const int rr = lane >> 2;
    const int c = lane & 3;
    float s = bp[c];
    const int krow = (56 + rr) * QK_STRIDE;
    #pragma unroll
    for (int d = 0; d < 64; ++d) {
      float kv = bf2f(ksh[krow + d]) + bf2f(ksl[krow + d]);
      s += kv * Wp[d * 4 + c];
    }
    promf[lane] = s;
  }
  __syncthreads();

  // ---------------- P4: gather policy[:, indices] ------------------------------
  float* outb = out + (size_t)b * n_idx;
  for (int i = tid; i < n_idx; i += 512) {
    int idx = idxs[i];
    float v;
    if (idx < 4096) {
      v = sc[idx];
    } else {
      int f = idx - 4096;        // flat index into promotion (8,24)==(3,64)
      int r = f / 24;
      int j = f - r * 24;
      int jj = j / 3;
      int cc = j - jj * 3;
      v = sc[(48 + r) * 64 + 56 + jj] + promf[jj * 4 + cc] + promf[jj * 4 + 3];
    }
    outb[i] = v;
  }
}

extern "C" void kernel_launch(void* const* d_in, const int* in_sizes, int n_in,
                              void* d_out, int out_size, void* d_ws, size_t ws_size,
                              hipStream_t stream) {
  const float* x  = (const float*)d_in[0];
  const float* W1 = (const float*)d_in[1];
  const float* b1 = (const float*)d_in[2];
  const float* Wq = (const float*)d_in[3];
  const float* bq = (const float*)d_in[4];
  const float* Wk = (const float*)d_in[5];
  const float* bk = (const float*)d_in[6];
  const float* Wp = (const float*)d_in[7];
  const float* bp = (const float*)d_in[8];
  const int* idxs = (const int*)d_in[9];

  const int B = in_sizes[0] / (64 * DM);   // 2048
  const int n_idx = in_sizes[9];           // 1858

  unsigned short* W1t = (unsigned short*)d_ws;        // [768][768] bf16 transposed
  unsigned short* Wqt = W1t + 768 * 768;              // [64][768]
  unsigned short* Wkt = Wqt + 64 * 768;               // [64][768]

  cvt_transpose<<<(768 * 768 + 255) / 256, 256, 0, stream>>>(W1, W1t, 768, 768);
  cvt_transpose<<<(64 * 768 + 255) / 256, 256, 0, stream>>>(Wq, Wqt, 768, 64);
  cvt_transpose<<<(64 * 768 + 255) / 256, 256, 0, stream>>>(Wk, Wkt, 768, 64);

  fused_policy<<<B, 512, 0, stream>>>(x, b1, bq, bk, Wp, bp, idxs, n_idx,
                                      W1t, Wqt, Wkt, (float*)d_out);
}

// Round 2
// 771.770 us; speedup vs baseline: 1.3303x; 1.3303x over previous
//
#include <hip/hip_runtime.h>

typedef __attribute__((ext_vector_type(8))) short short8;   // 8 bf16 = 4 VGPRs (MFMA A/B frag)
typedef __attribute__((ext_vector_type(4))) float f32x4;    // MFMA C/D frag
typedef __attribute__((ext_vector_type(4))) short short4v;

#define DM 768
#define DP 64

__device__ __forceinline__ unsigned short f2bf(float f) {
  unsigned u = __float_as_uint(f);
  u = u + 0x7fffu + ((u >> 16) & 1u);          // RNE
  return (unsigned short)(u >> 16);
}
__device__ __forceinline__ float bf2f(unsigned short s) {
  return __uint_as_float(((unsigned)s) << 16);
}
// mish(v) = v*tanh(softplus(v)) = v*(t^2+2t)/(t^2+2t+2), t=e^v (exact algebra, one exp)
__device__ __forceinline__ float mishf(float v) {
  float t = __expf(fminf(v, 30.0f));
  float num = t * (t + 2.0f);
  return v * (num / (num + 2.0f));
}

// Pre-pack weight [768,N] fp32 into MFMA B-fragment order, bf16:
//   dst[((kt*(N/16) + nt)*64 + lane)*8 + j] = bf16(src[(kt*32 + (lane>>4)*8 + j)*N + nt*16 + (lane&15)])
// so the hot loop's B-frag load is one coalesced 16B/lane read.
__global__ void cvt_frag(const float* __restrict__ src, unsigned short* __restrict__ dst,
                         int N, int ntPer) {
  constexpr int MAXC = 192;
  constexpr int TS = MAXC + 8;
  __shared__ unsigned short tile[32 * TS];
  const int kt = blockIdx.x;
  const int nt0 = blockIdx.y * ntPer;
  const int cols = ntPer * 16;
  for (int e = threadIdx.x; e < 32 * cols; e += blockDim.x) {
    int row = e / cols, col = e - row * cols;
    tile[row * TS + col] = f2bf(src[(kt * 32 + row) * N + nt0 * 16 + col]);
  }
  __syncthreads();
  const int NT = N / 16;
  for (int s = threadIdx.x; s < ntPer * 64; s += blockDim.x) {
    int ntl = s >> 6, l = s & 63;
    int m16 = l & 15, quad = l >> 4;
    short8 v;
    #pragma unroll
    for (int j = 0; j < 8; ++j)
      v[j] = (short)tile[(quad * 8 + j) * TS + ntl * 16 + m16];
    *(short8*)(dst + ((size_t)((kt * NT + nt0 + ntl) * 64 + l)) * 8) = v;
  }
}

__global__ __launch_bounds__(1024, 4) void fused_policy(
    const float* __restrict__ x, const float* __restrict__ b1,
    const float* __restrict__ bq, const float* __restrict__ bk,
    const float* __restrict__ Wp, const float* __restrict__ bp,
    const int* __restrict__ idxs, int n_idx,
    const unsigned short* __restrict__ W1f,   // frag-packed [24][48][64][8]
    const unsigned short* __restrict__ Wqf,   // frag-packed [24][4][64][8]
    const unsigned short* __restrict__ Wkf,   // frag-packed [24][4][64][8]
    float* __restrict__ out) {
  constexpr int XS  = 136;   // x chunk row stride (shorts): 64x128 bf16 +8 pad
  constexpr int HSS = 776;   // hs row stride (shorts): 768 + 8
  constexpr int QKS = 72;    // q/k row stride (shorts)

  __shared__ __align__(16) unsigned char smemA[64 * HSS * 2];       // 99,328 B
  __shared__ __align__(16) unsigned short qkbuf[4][64 * QKS];       // 36,864 B
  __shared__ float promf[32];

  unsigned short* hs  = (unsigned short*)smemA;                 // live P1-epi .. P2
  unsigned short* xs0 = (unsigned short*)smemA;                 // live during P1 K-loop
  unsigned short* xs1 = xs0 + 64 * XS;
  float* sc = (float*)smemA;                                    // live P3 .. P4
  unsigned short* qsh = qkbuf[0];
  unsigned short* qsl = qkbuf[1];
  unsigned short* ksh = qkbuf[2];
  unsigned short* ksl = qkbuf[3];

  const int b    = blockIdx.x;
  const int tid  = threadIdx.x;
  const int wave = tid >> 6;
  const int lane = tid & 63;
  const int m16  = lane & 15;
  const int quad = lane >> 4;

  const float* xb = x + (size_t)b * (64 * DM);

  // ---------------- P1: h = mish(x@W1 + b1), all 64x768 of h in block registers --
  f32x4 acc[4][3];
  #pragma unroll
  for (int rt = 0; rt < 4; ++rt)
    #pragma unroll
    for (int ct = 0; ct < 3; ++ct)
      #pragma unroll
      for (int r = 0; r < 4; ++r) acc[rt][ct][r] = 0.0f;

  float b1v[3];
  #pragma unroll
  for (int ct = 0; ct < 3; ++ct) b1v[ct] = b1[wave * 48 + ct * 16 + m16];

  // per-wave frag base: frag(kt,ct) = wb + kt*48*64*8 + ct*64*8
  const unsigned short* wb = W1f + ((size_t)(wave * 3) * 64 + lane) * 8;
  short8 bcur[3], bnxt[3];
  #pragma unroll
  for (int ct = 0; ct < 3; ++ct) bcur[ct] = *(const short8*)(wb + ct * 512);

  // preload x chunk 0 into registers
  float4 pv0, pv1;
  {
    int e0 = tid, e1 = tid + 1024;
    pv0 = *(const float4*)(xb + (e0 >> 5) * DM + (e0 & 31) * 4);
    pv1 = *(const float4*)(xb + (e1 >> 5) * DM + (e1 & 31) * 4);
  }

  for (int c = 0; c < 6; ++c) {
    unsigned short* xw = (c & 1) ? xs1 : xs0;
    {  // convert + store staged chunk
      int e0 = tid, e1 = tid + 1024;
      short4v s4;
      s4.x = (short)f2bf(pv0.x); s4.y = (short)f2bf(pv0.y);
      s4.z = (short)f2bf(pv0.z); s4.w = (short)f2bf(pv0.w);
      *(short4v*)(xw + (e0 >> 5) * XS + (e0 & 31) * 4) = s4;
      s4.x = (short)f2bf(pv1.x); s4.y = (short)f2bf(pv1.y);
      s4.z = (short)f2bf(pv1.z); s4.w = (short)f2bf(pv1.w);
      *(short4v*)(xw + (e1 >> 5) * XS + (e1 & 31) * 4) = s4;
    }
    __syncthreads();
    if (c < 5) {  // issue next chunk's HBM loads; drain behind this chunk's MFMAs
      int kb = (c + 1) * 128;
      int e0 = tid, e1 = tid + 1024;
      pv0 = *(const float4*)(xb + (e0 >> 5) * DM + kb + (e0 & 31) * 4);
      pv1 = *(const float4*)(xb + (e1 >> 5) * DM + kb + (e1 & 31) * 4);
    }
    #pragma unroll
    for (int ks = 0; ks < 4; ++ks) {
      const int kt = c * 4 + ks;
      short8 af[4];
      #pragma unroll
      for (int rt = 0; rt < 4; ++rt)
        af[rt] = *(const short8*)(xw + (rt * 16 + m16) * XS + ks * 32 + quad * 8);
      if (kt < 23) {
        #pragma unroll
        for (int ct = 0; ct < 3; ++ct)
          bnxt[ct] = *(const short8*)(wb + (kt + 1) * 24576 + ct * 512);
      }
      #pragma unroll
      for (int rt = 0; rt < 4; ++rt)
        #pragma unroll
        for (int ct = 0; ct < 3; ++ct)
          acc[rt][ct] = __builtin_amdgcn_mfma_f32_16x16x32_bf16(af[rt], bcur[ct], acc[rt][ct], 0, 0, 0);
      if (kt < 23) {
        #pragma unroll
        for (int ct = 0; ct < 3; ++ct) bcur[ct] = bnxt[ct];
      }
    }
  }
  __syncthreads();   // xs region dead; hs (aliased) writes may begin

  // epilogue: bias + mish -> hs bf16. C/D layout: row=quad*4+r, col=m16
  #pragma unroll
  for (int rt = 0; rt < 4; ++rt)
    #pragma unroll
    for (int ct = 0; ct < 3; ++ct)
      #pragma unroll
      for (int r = 0; r < 4; ++r) {
        int row = rt * 16 + quad * 4 + r;
        int col = wave * 48 + ct * 16 + m16;
        hs[row * HSS + col] = f2bf(mishf(acc[rt][ct][r] + b1v[ct]));
      }
  __syncthreads();

  // ---------------- P2: q (waves 0-7), k (waves 8-15); hi/lo bf16 split ---------
  {
    const int grp = wave >> 3;
    const int w8 = wave & 7;
    const int rt = w8 & 3;
    const int ch = w8 >> 2;                 // which 32-col half of the 64 outputs
    const unsigned short* Wf = grp ? Wkf : Wqf;
    const float* bias = grp ? bk : bq;
    unsigned short* oh = grp ? ksh : qsh;
    unsigned short* ol = grp ? ksl : qsl;

    f32x4 acc2[2];
    #pragma unroll
    for (int ct2 = 0; ct2 < 2; ++ct2)
      #pragma unroll
      for (int r = 0; r < 4; ++r) acc2[ct2][r] = 0.0f;

    const unsigned short* wfb = Wf + ((size_t)(ch * 2) * 64 + lane) * 8;
    short8 c2[2], n2[2];
    #pragma unroll
    for (int ct2 = 0; ct2 < 2; ++ct2) c2[ct2] = *(const short8*)(wfb + ct2 * 512);

    const int arow = (rt * 16 + m16) * HSS;
    short8 a = *(const short8*)(hs + arow + quad * 8);
    for (int kt = 0; kt < 24; ++kt) {
      short8 an;
      if (kt < 23) {
        an = *(const short8*)(hs + arow + (kt + 1) * 32 + quad * 8);
        #pragma unroll
        for (int ct2 = 0; ct2 < 2; ++ct2)
          n2[ct2] = *(const short8*)(wfb + (kt + 1) * 2048 + ct2 * 512);
      }
      #pragma unroll
      for (int ct2 = 0; ct2 < 2; ++ct2)
        acc2[ct2] = __builtin_amdgcn_mfma_f32_16x16x32_bf16(a, c2[ct2], acc2[ct2], 0, 0, 0);
      if (kt < 23) {
        a = an;
        #pragma unroll
        for (int ct2 = 0; ct2 < 2; ++ct2) c2[ct2] = n2[ct2];
      }
    }
    #pragma unroll
    for (int ct2 = 0; ct2 < 2; ++ct2)
      #pragma unroll
      for (int r = 0; r < 4; ++r) {
        int row = rt * 16 + quad * 4 + r;
        int col = ch * 32 + ct2 * 16 + m16;
        float v = acc2[ct2][r] + bias[col];
        unsigned short vh = f2bf(v);
        unsigned short vl = f2bf(v - bf2f(vh));
        oh[row * QKS + col] = vh;
        ol[row * QKS + col] = vl;
      }
  }
  __syncthreads();

  // ---------------- P3: scores = q@k^T * 0.125 (16 tiles / 16 waves) -----------
  {
    const int rt = wave >> 2, ctt = wave & 3;
    f32x4 a3;
    #pragma unroll
    for (int r = 0; r < 4; ++r) a3[r] = 0.0f;
    #pragma unroll
    for (int kt = 0; kt < 2; ++kt) {
      const int k0 = kt * 32;
      short8 ah = *(const short8*)(qsh + (rt * 16 + m16) * QKS + k0 + quad * 8);
      short8 al = *(const short8*)(qsl + (rt * 16 + m16) * QKS + k0 + quad * 8);
      short8 bh = *(const short8*)(ksh + (ctt * 16 + m16) * QKS + k0 + quad * 8);
      short8 bl = *(const short8*)(ksl + (ctt * 16 + m16) * QKS + k0 + quad * 8);
      a3 = __builtin_amdgcn_mfma_f32_16x16x32_bf16(ah, bh, a3, 0, 0, 0);
      a3 = __builtin_amdgcn_mfma_f32_16x16x32_bf16(ah, bl, a3, 0, 0, 0);
      a3 = __builtin_amdgcn_mfma_f32_16x16x32_bf16(al, bh, a3, 0, 0, 0);
    }
    #pragma unroll
    for (int r = 0; r < 4; ++r)
      sc[(rt * 16 + quad * 4 + r) * 64 + ctt * 16 + m16] = a3[r] * 0.125f;

    if (wave == 15 && lane < 32) {
      // promf[rr][c] = bp[c] + sum_d k[56+rr][d] * Wp[d][c]
      const int rr = lane >> 2;
      const int c = lane & 3;
      float s = bp[c];
      const int krow = (56 + rr) * QKS;
      #pragma unroll
      for (int d = 0; d < 64; ++d) {
        float kv = bf2f(ksh[krow + d]) + bf2f(ksl[krow + d]);
        s += kv * Wp[d * 4 + c];
      }
      promf[lane] = s;
    }
  }
  __syncthreads();

  // ---------------- P4: gather policy[:, indices] ------------------------------
  float* outb = out + (size_t)b * n_idx;
  for (int i = tid; i < n_idx; i += 1024) {
    int idx = idxs[i];
    float v;
    if (idx < 4096) {
      v = sc[idx];
    } else {
      int f = idx - 4096;        // flat index into promotion (8,24)==(3,64)
      int r = f / 24;
      int j = f - r * 24;
      int jj = j / 3;
      int cc = j - jj * 3;
      v = sc[(48 + r) * 64 + 56 + jj] + promf[jj * 4 + cc] + promf[jj * 4 + 3];
    }
    outb[i] = v;
  }
}

extern "C" void kernel_launch(void* const* d_in, const int* in_sizes, int n_in,
                              void* d_out, int out_size, void* d_ws, size_t ws_size,
                              hipStream_t stream) {
  const float* x  = (const float*)d_in[0];
  const float* W1 = (const float*)d_in[1];
  const float* b1 = (const float*)d_in[2];
  const float* Wq = (const float*)d_in[3];
  const float* bq = (const float*)d_in[4];
  const float* Wk = (const float*)d_in[5];
  const float* bk = (const float*)d_in[6];
  const float* Wp = (const float*)d_in[7];
  const float* bp = (const float*)d_in[8];
  const int* idxs = (const int*)d_in[9];

  const int B = in_sizes[0] / (64 * DM);   // 2048
  const int n_idx = in_sizes[9];           // 1858

  unsigned short* W1f = (unsigned short*)d_ws;        // [24][48][64][8] bf16 frags
  unsigned short* Wqf = W1f + 768 * 768;              // [24][4][64][8]
  unsigned short* Wkf = Wqf + 64 * 768;

  cvt_frag<<<dim3(24, 4), 256, 0, stream>>>(W1, W1f, 768, 12);
  cvt_frag<<<dim3(24, 1), 256, 0, stream>>>(Wq, Wqf, 64, 4);
  cvt_frag<<<dim3(24, 1), 256, 0, stream>>>(Wk, Wkf, 64, 4);

  fused_policy<<<B, 1024, 0, stream>>>(x, b1, bq, bk, Wp, bp, idxs, n_idx,
                                       W1f, Wqf, Wkf, (float*)d_out);
}